// Round 1
// baseline (313.911 us; speedup 1.0000x reference)
//
#include <hip/hip_runtime.h>
#include <math.h>

// Problem constants (match reference setup_inputs)
#define BB 8
#define TT 4096
#define DD 512
#define EE 64
#define HH 4
#define G1 256      // D/2
#define TP 16       // positions per block

__device__ __forceinline__ float dot4(float4 a, float4 b) {
    return a.x * b.x + a.y * b.y + a.z * b.z + a.w * b.w;
}

__global__ __launch_bounds__(256) void engram_fused(
    const int*   __restrict__ tok,     // [B,T]
    const float* __restrict__ hidden,  // [B,T,D]
    const float* __restrict__ emb,     // [H,HR,E]
    const float* __restrict__ W_hid,   // [D,E]
    const float* __restrict__ b_hid,   // [D]
    const float* __restrict__ W_g1,    // [G1,D]
    const float* __restrict__ b_g1,    // [G1]
    const float* __restrict__ W_g2,    // [1,G1]
    const float* __restrict__ b_g2,    // [1]
    const int*   __restrict__ seeds,   // [H]
    const int*   __restrict__ p_hr,    // scalar
    const int*   __restrict__ p_mn,    // scalar
    float*       __restrict__ out)     // [B,T,D]
{
    __shared__ int   sIdx[TP][3][HH];
    __shared__ float sMem[TP][EE];
    __shared__ float sG[TP][DD];
    __shared__ float sG1[TP][G1];
    __shared__ float sGate[TP];

    const int tid = threadIdx.x;
    const int pg0 = blockIdx.x * TP;     // first global position of this tile
    const int b   = pg0 / TT;
    const int t0  = pg0 % TT;            // TP divides TT -> tile never crosses rows
    const int HR  = *p_hr;
    int NN = *p_mn - 1;                  // number of n values (n = 2..max_n)
    if (NN > 3) NN = 3;
    if (NN < 0) NN = 0;

    // ---- Stage 1: hash indices (replicates reference fp32 arithmetic exactly)
    if (tid < TP) {
        const int p = tid;
        const int t = t0 + p;
        const int* trow = tok + b * TT;
        for (int h = 0; h < HH; ++h) {
            const float sd = (float)(seeds[h] + 1);
            float w = (float)trow[t] * sd;          // scaled[t]
            for (int j = 0; j < NN; ++j) {
                const int n = j + 2;
                int idx = -1;
                if (t <= TT - n) {
                    w = w + (float)trow[t + n - 1] * sd;   // ((s0+s1)+s2) ordering
                    idx = ((int)w) % HR;                   // trunc-to-zero, non-neg
                }
                sIdx[p][j][h] = idx;
            }
        }
    }
    __syncthreads();

    // ---- Stage 2: gather + head-mean + n-sum -> sMem[p][e]
    {
        const int p = tid >> 4;      // 16 threads per position
        const int q = tid & 15;      // each covers 4 consecutive floats of E=64
        const float invH = 1.0f / (float)HH;
        float4 acc = make_float4(0.f, 0.f, 0.f, 0.f);
        for (int j = 0; j < NN; ++j) {
            float4 a = make_float4(0.f, 0.f, 0.f, 0.f);
            #pragma unroll
            for (int h = 0; h < HH; ++h) {
                const int idx = sIdx[p][j][h];
                if (idx >= 0) {
                    const float4 v = *(const float4*)&emb[((size_t)h * (size_t)HR + (size_t)idx) * EE + q * 4];
                    a.x += v.x; a.y += v.y; a.z += v.z; a.w += v.w;
                }
            }
            acc.x += a.x * invH; acc.y += a.y * invH;
            acc.z += a.z * invH; acc.w += a.w * invH;
        }
        *(float4*)&sMem[p][q * 4] = acc;
    }
    __syncthreads();

    // ---- Stage 3: memory_proj for d0 = tid, d1 = tid+256; g = hidden + proj -> sG
    float acc0[TP], acc1[TP], hid0[TP], hid1[TP];
    const int d0 = tid, d1 = tid + 256;
    #pragma unroll
    for (int p = 0; p < TP; ++p) { acc0[p] = 0.f; acc1[p] = 0.f; }

    #pragma unroll
    for (int e4 = 0; e4 < EE / 4; ++e4) {
        const float4 w0 = *(const float4*)&W_hid[d0 * EE + e4 * 4];
        const float4 w1 = *(const float4*)&W_hid[d1 * EE + e4 * 4];
        #pragma unroll
        for (int p = 0; p < TP; ++p) {
            const float4 s = *(const float4*)&sMem[p][e4 * 4];
            acc0[p] += dot4(s, w0);
            acc1[p] += dot4(s, w1);
        }
    }
    {
        const float bh0 = b_hid[d0], bh1 = b_hid[d1];
        #pragma unroll
        for (int p = 0; p < TP; ++p) {
            const size_t row = ((size_t)pg0 + p) * DD;
            hid0[p] = hidden[row + d0];
            hid1[p] = hidden[row + d1];
            acc0[p] += bh0;
            acc1[p] += bh1;
            sG[p][d0] = hid0[p] + acc0[p];
            sG[p][d1] = hid1[p] + acc1[p];
        }
    }
    __syncthreads();

    // ---- Stage 4: g1[p][h] = gelu(dot512(g[p], W_g1[h]) + b_g1[h]); thread = h
    {
        float acc2[TP];
        #pragma unroll
        for (int p = 0; p < TP; ++p) acc2[p] = 0.f;
        const float* wrow = &W_g1[tid * DD];
        for (int d4 = 0; d4 < DD / 4; ++d4) {
            const float4 w = *(const float4*)&wrow[d4 * 4];
            #pragma unroll
            for (int p = 0; p < TP; ++p) {
                const float4 g = *(const float4*)&sG[p][d4 * 4];   // LDS broadcast
                acc2[p] += dot4(g, w);
            }
        }
        const float bg = b_g1[tid];
        #pragma unroll
        for (int p = 0; p < TP; ++p) {
            const float x = acc2[p] + bg;
            sG1[p][tid] = 0.5f * x * (1.0f + erff(x * 0.70710678118654752f));
        }
    }
    __syncthreads();

    // ---- Stage 5: gate[p] = sigmoid(dot256(g1[p], W_g2) + b_g2)
    {
        const int p = tid >> 4;
        const int q = tid & 15;
        float partial = 0.f;
        #pragma unroll
        for (int k = 0; k < 16; ++k)
            partial += sG1[p][q * 16 + k] * W_g2[q * 16 + k];
        partial += __shfl_xor(partial, 1, 16);
        partial += __shfl_xor(partial, 2, 16);
        partial += __shfl_xor(partial, 4, 16);
        partial += __shfl_xor(partial, 8, 16);
        if (q == 0) {
            const float x = partial + b_g2[0];
            sGate[p] = 1.0f / (1.0f + expf(-x));
        }
    }
    __syncthreads();

    // ---- Stage 6: out = hidden + gate * memory_proj (proj still in registers)
    #pragma unroll
    for (int p = 0; p < TP; ++p) {
        const size_t row = ((size_t)pg0 + p) * DD;
        const float gt = sGate[p];
        out[row + d0] = hid0[p] + gt * acc0[p];
        out[row + d1] = hid1[p] + gt * acc1[p];
    }
}

extern "C" void kernel_launch(void* const* d_in, const int* in_sizes, int n_in,
                              void* d_out, int out_size, void* d_ws, size_t ws_size,
                              hipStream_t stream) {
    const int*   tok    = (const int*)  d_in[0];
    const float* hidden = (const float*)d_in[1];
    const float* emb    = (const float*)d_in[2];
    const float* W_hid  = (const float*)d_in[3];
    const float* b_hid  = (const float*)d_in[4];
    const float* W_g1   = (const float*)d_in[5];
    const float* b_g1   = (const float*)d_in[6];
    const float* W_g2   = (const float*)d_in[7];
    const float* b_g2   = (const float*)d_in[8];
    const int*   seeds  = (const int*)  d_in[9];
    const int*   p_hr   = (const int*)  d_in[10];
    const int*   p_mn   = (const int*)  d_in[11];
    float* out = (float*)d_out;

    const int npos = in_sizes[1] / DD;   // B*T
    dim3 grid(npos / TP), block(256);
    engram_fused<<<grid, block, 0, stream>>>(tok, hidden, emb, W_hid, b_hid,
                                             W_g1, b_g1, W_g2, b_g2,
                                             seeds, p_hr, p_mn, out);
}

// Round 2
// 139.648 us; speedup vs baseline: 2.2479x; 2.2479x over previous
//
#include <hip/hip_runtime.h>
#include <math.h>

// Problem constants (match reference setup_inputs)
#define BB 8
#define TT 4096
#define DD 512
#define EE 64
#define HH 4
#define G1 256      // D/2
#define TP 64       // positions per block
#define NWAVE 4

typedef short  s16x8 __attribute__((ext_vector_type(8)));
typedef short  s16x4 __attribute__((ext_vector_type(4)));
typedef float  f32x4 __attribute__((ext_vector_type(4)));

__device__ __forceinline__ unsigned short f2bf(float f) {
    union { float f; unsigned u; } v; v.f = f;
    unsigned r = v.u + 0x7FFFu + ((v.u >> 16) & 1u);   // RNE
    return (unsigned short)(r >> 16);
}
__device__ __forceinline__ float bf2f(unsigned short b) {
    union { unsigned u; float f; } v; v.u = ((unsigned)b) << 16;
    return v.f;
}

// ---- pre-pass: convert W_hid [512][64] and W_g1 [256][512] to bf16 in ws
__global__ __launch_bounds__(256) void convert_weights(
    const float* __restrict__ W_hid, const float* __restrict__ W_g1,
    unsigned short* __restrict__ ws) {
    int i = blockIdx.x * 256 + threadIdx.x;
    if (i < DD * EE)  ws[i] = f2bf(W_hid[i]);
    if (i < G1 * DD)  ws[DD * EE + i] = f2bf(W_g1[i]);
}

__global__ __launch_bounds__(256, 2) void engram_mfma(
    const int*   __restrict__ tok,     // [B,T]
    const float* __restrict__ hidden,  // [B,T,D]
    const float* __restrict__ emb,     // [H,HR,E]
    const float* __restrict__ b_hid,   // [D]
    const float* __restrict__ b_g1,    // [G1]
    const float* __restrict__ W_g2,    // [1,G1]
    const float* __restrict__ b_g2,    // [1]
    const int*   __restrict__ seeds,   // [H]
    const int*   __restrict__ p_hr,
    const int*   __restrict__ p_mn,
    const unsigned short* __restrict__ ws_bf,  // W_hid bf16 | W_g1 bf16
    float*       __restrict__ out)     // [B,T,D]
{
    __shared__ int   sIdx[TP][3][HH];
    __shared__ __align__(16) unsigned char sMemb[TP * 128];   // seq_mem bf16 [64][64], swizzled
    __shared__ __align__(16) unsigned char sGb[TP * 1024];    // g bf16 [64][512], swizzled
    __shared__ float sGpart[NWAVE][TP];
    __shared__ float sGate[TP];

    const int tid  = threadIdx.x;
    const int lane = tid & 63;
    const int wave = tid >> 6;
    const int lr   = lane & 15;   // operand row / C col (position)
    const int lg   = lane >> 4;   // k-group / C row-quad
    const int pg0  = blockIdx.x * TP;
    const int b    = pg0 / TT;
    const int t0   = pg0 % TT;
    const int HR   = *p_hr;
    int NN = *p_mn - 1;
    if (NN > 3) NN = 3;
    if (NN < 0) NN = 0;

    const unsigned short* ws_whid = ws_bf;             // [512][64]
    const unsigned short* ws_wg1  = ws_bf + DD * EE;   // [256][512]

    // ---- P1: hash indices. tid = p*4 + h. Bit-exact fp32 replication of reference.
    {
        const int p = tid >> 2, h = tid & 3;
        const int t = t0 + p;
        const int* trow = tok + b * TT;
        const float sd = (float)(seeds[h] + 1);
        float w = (float)trow[t] * sd;
        for (int j = 0; j < NN; ++j) {
            const int n = j + 2;
            int idx = -1;
            if (t <= TT - n) {
                w = w + (float)trow[t + n - 1] * sd;
                idx = ((int)w) % HR;
            }
            sIdx[p][j][h] = idx;
        }
    }
    __syncthreads();

    // ---- P2: gather + head-mean + n-sum -> sMem bf16 [p][64] (swizzled)
    {
        const int p = tid >> 2, q = tid & 3;   // q covers e = q*16 .. q*16+15
        float acc[16];
        #pragma unroll
        for (int k = 0; k < 16; ++k) acc[k] = 0.f;
        for (int j = 0; j < NN; ++j) {
            #pragma unroll
            for (int h = 0; h < HH; ++h) {
                const int idx = sIdx[p][j][h];
                if (idx >= 0) {
                    const float* er = emb + ((size_t)h * 262144u + (size_t)idx) * EE + q * 16;
                    #pragma unroll
                    for (int v = 0; v < 4; ++v) {
                        const float4 f = *(const float4*)(er + v * 4);
                        acc[v*4+0] += f.x; acc[v*4+1] += f.y;
                        acc[v*4+2] += f.z; acc[v*4+3] += f.w;
                    }
                }
            }
        }
        unsigned short bv[16];
        #pragma unroll
        for (int k = 0; k < 16; ++k) bv[k] = f2bf(acc[k] * 0.25f);
        #pragma unroll
        for (int half = 0; half < 2; ++half) {
            const int c = q * 32 + half * 16;
            s16x8 pk;
            #pragma unroll
            for (int k = 0; k < 8; ++k) pk[k] = (short)bv[half*8 + k];
            *(s16x8*)(sMemb + p * 128 + (c ^ ((p & 7) << 4))) = pk;
        }
    }
    __syncthreads();

    // ---- P3: projT[d][p] = W_hid_bf[d][:] x memT ; g = hidden + proj + b_hid -> sG (bf16, swizzled)
    {
        s16x8 bfrag[4][2];
        #pragma unroll
        for (int Nt = 0; Nt < 4; ++Nt)
            #pragma unroll
            for (int ks = 0; ks < 2; ++ks) {
                const int p = Nt * 16 + lr;
                const int c = ks * 64 + lg * 16;
                bfrag[Nt][ks] = *(const s16x8*)(sMemb + p * 128 + (c ^ ((p & 7) << 4)));
            }
        for (int m = 0; m < 8; ++m) {
            const int Mt = wave * 8 + m;
            const int drow = Mt * 16 + lr;
            s16x8 afrag[2];
            #pragma unroll
            for (int ks = 0; ks < 2; ++ks)
                afrag[ks] = *(const s16x8*)(ws_whid + drow * EE + ks * 32 + lg * 8);
            #pragma unroll
            for (int Nt = 0; Nt < 4; ++Nt) {
                f32x4 c = {0.f, 0.f, 0.f, 0.f};
                c = __builtin_amdgcn_mfma_f32_16x16x32_bf16(afrag[0], bfrag[Nt][0], c, 0, 0, 0);
                c = __builtin_amdgcn_mfma_f32_16x16x32_bf16(afrag[1], bfrag[Nt][1], c, 0, 0, 0);
                // lane holds C[d = Mt*16+lg*4+r][p = Nt*16+lr]
                const int p_c = Nt * 16 + lr;
                const int d0  = Mt * 16 + lg * 4;
                const float4 hv = *(const float4*)&hidden[(size_t)(pg0 + p_c) * DD + d0];
                const float4 bh = *(const float4*)&b_hid[d0];
                s16x4 gp;
                gp[0] = (short)f2bf(hv.x + c[0] + bh.x);
                gp[1] = (short)f2bf(hv.y + c[1] + bh.y);
                gp[2] = (short)f2bf(hv.z + c[2] + bh.z);
                gp[3] = (short)f2bf(hv.w + c[3] + bh.w);
                const int cb = d0 * 2;
                *(s16x4*)(sGb + p_c * 1024 + (cb ^ ((p_c & 31) << 4))) = gp;
            }
        }
    }
    __syncthreads();

    // ---- P4: g1T[h][p] GEMM over K=512, consume into gate partials
    {
        float pgate[4] = {0.f, 0.f, 0.f, 0.f};
        #pragma unroll
        for (int Nt = 0; Nt < 4; ++Nt) {
            s16x8 gb[16];
            #pragma unroll
            for (int ks = 0; ks < 16; ++ks) {
                const int p = Nt * 16 + lr;
                const int c = ks * 64 + lg * 16;
                gb[ks] = *(const s16x8*)(sGb + p * 1024 + (c ^ ((p & 31) << 4)));
            }
            #pragma unroll
            for (int m = 0; m < 4; ++m) {
                const int Mt = wave * 4 + m;
                const int h0row = Mt * 16 + lr;
                const unsigned short* wg = ws_wg1 + (size_t)h0row * DD;
                f32x4 c = {0.f, 0.f, 0.f, 0.f};
                #pragma unroll
                for (int ks = 0; ks < 16; ++ks) {
                    const s16x8 a = *(const s16x8*)(wg + ks * 32 + lg * 8);
                    c = __builtin_amdgcn_mfma_f32_16x16x32_bf16(a, gb[ks], c, 0, 0, 0);
                }
                // lane holds C[h = Mt*16+lg*4+r][p = Nt*16+lr]
                const int h0 = Mt * 16 + lg * 4;
                const float4 bg = *(const float4*)&b_g1[h0];
                const float4 w2 = *(const float4*)&W_g2[h0];
                #pragma unroll
                for (int r = 0; r < 4; ++r) {
                    const float x = c[r] + ((const float*)&bg)[r];
                    const float gl = 0.5f * x * (1.0f + erff(x * 0.70710678118654752f));
                    pgate[Nt] += gl * ((const float*)&w2)[r];
                }
            }
        }
        #pragma unroll
        for (int Nt = 0; Nt < 4; ++Nt) {
            pgate[Nt] += __shfl_xor(pgate[Nt], 16);
            pgate[Nt] += __shfl_xor(pgate[Nt], 32);
        }
        if (lane < 16) {
            #pragma unroll
            for (int Nt = 0; Nt < 4; ++Nt)
                sGpart[wave][Nt * 16 + lane] = pgate[Nt];
        }
    }
    __syncthreads();
    if (tid < TP) {
        const float s = sGpart[0][tid] + sGpart[1][tid] + sGpart[2][tid] + sGpart[3][tid] + b_g2[0];
        sGate[tid] = 1.0f / (1.0f + expf(-s));
    }
    __syncthreads();

    // ---- P6: out = hidden + gate*(g - hidden)
    {
        const int tq = tid & 15;          // 16 threads per position
        const int tp = tid >> 4;          // position within chunk
        for (int c4 = 0; c4 < 4; ++c4) {
            const int p  = c4 * 16 + tp;
            const float gt = sGate[p];
            const float* hp = &hidden[(size_t)(pg0 + p) * DD];
            float*       op = &out[(size_t)(pg0 + p) * DD];
            #pragma unroll
            for (int i = 0; i < 4; ++i) {
                const int d  = tq * 8 + i * 128;
                const int cb = d * 2;
                const s16x8 gv = *(const s16x8*)(sGb + p * 1024 + (cb ^ ((p & 31) << 4)));
                const float4 h0 = *(const float4*)(hp + d);
                const float4 h1 = *(const float4*)(hp + d + 4);
                float4 o0, o1;
                o0.x = h0.x + gt * (bf2f((unsigned short)gv[0]) - h0.x);
                o0.y = h0.y + gt * (bf2f((unsigned short)gv[1]) - h0.y);
                o0.z = h0.z + gt * (bf2f((unsigned short)gv[2]) - h0.z);
                o0.w = h0.w + gt * (bf2f((unsigned short)gv[3]) - h0.w);
                o1.x = h1.x + gt * (bf2f((unsigned short)gv[4]) - h1.x);
                o1.y = h1.y + gt * (bf2f((unsigned short)gv[5]) - h1.y);
                o1.z = h1.z + gt * (bf2f((unsigned short)gv[6]) - h1.z);
                o1.w = h1.w + gt * (bf2f((unsigned short)gv[7]) - h1.w);
                *(float4*)(op + d)     = o0;
                *(float4*)(op + d + 4) = o1;
            }
        }
    }
}

extern "C" void kernel_launch(void* const* d_in, const int* in_sizes, int n_in,
                              void* d_out, int out_size, void* d_ws, size_t ws_size,
                              hipStream_t stream) {
    const int*   tok    = (const int*)  d_in[0];
    const float* hidden = (const float*)d_in[1];
    const float* emb    = (const float*)d_in[2];
    const float* W_hid  = (const float*)d_in[3];
    const float* b_hid  = (const float*)d_in[4];
    const float* W_g1   = (const float*)d_in[5];
    const float* b_g1   = (const float*)d_in[6];
    const float* W_g2   = (const float*)d_in[7];
    const float* b_g2   = (const float*)d_in[8];
    const int*   seeds  = (const int*)  d_in[9];
    const int*   p_hr   = (const int*)  d_in[10];
    const int*   p_mn   = (const int*)  d_in[11];
    float* out = (float*)d_out;
    unsigned short* ws_bf = (unsigned short*)d_ws;

    convert_weights<<<dim3((G1 * DD + 255) / 256), dim3(256), 0, stream>>>(W_hid, W_g1, ws_bf);

    const int npos = in_sizes[1] / DD;   // B*T
    engram_mfma<<<dim3(npos / TP), dim3(256), 0, stream>>>(
        tok, hidden, emb, b_hid, b_g1, W_g2, b_g2, seeds, p_hr, p_mn, ws_bf, out);
}

// Round 3
// 105.311 us; speedup vs baseline: 2.9808x; 1.3261x over previous
//
#include <hip/hip_runtime.h>
#include <math.h>

// Problem constants (match reference setup_inputs)
#define TT 4096
#define DD 512
#define EE 64
#define HH 4
#define G1 256      // D/2
#define TP 32       // positions per block
#define NWAVE 4

typedef short  s16x8 __attribute__((ext_vector_type(8)));
typedef short  s16x4 __attribute__((ext_vector_type(4)));
typedef float  f32x4 __attribute__((ext_vector_type(4)));

__device__ __forceinline__ unsigned short f2bf(float f) {
    union { float f; unsigned u; } v; v.f = f;
    unsigned r = v.u + 0x7FFFu + ((v.u >> 16) & 1u);   // RNE
    return (unsigned short)(r >> 16);
}
__device__ __forceinline__ float bf2f(unsigned short b) {
    union { unsigned u; float f; } v; v.u = ((unsigned)b) << 16;
    return v.f;
}

// ---- pre-pass: convert W_hid [512][64] and W_g1 [256][512] to bf16 in ws
__global__ __launch_bounds__(256) void convert_weights(
    const float* __restrict__ W_hid, const float* __restrict__ W_g1,
    unsigned short* __restrict__ ws) {
    int i = blockIdx.x * 256 + threadIdx.x;
    if (i < DD * EE)  ws[i] = f2bf(W_hid[i]);
    if (i < G1 * DD)  ws[DD * EE + i] = f2bf(W_g1[i]);
}

__global__ __launch_bounds__(256, 4) void engram_mfma(
    const int*   __restrict__ tok,     // [B,T]
    const float* __restrict__ hidden,  // [B,T,D]
    const float* __restrict__ emb,     // [H,HR,E]
    const float* __restrict__ b_hid,   // [D]
    const float* __restrict__ b_g1,    // [G1]
    const float* __restrict__ W_g2,    // [1,G1]
    const float* __restrict__ b_g2,    // [1]
    const int*   __restrict__ seeds,   // [H]
    const int*   __restrict__ p_hr,
    const int*   __restrict__ p_mn,
    const unsigned short* __restrict__ ws_bf,  // W_hid bf16 | W_g1 bf16
    float*       __restrict__ out)     // [B,T,D]
{
    __shared__ int   sIdx[TP][3][HH];
    __shared__ __align__(16) unsigned char sMemb[TP * 128];   // seq_mem bf16 [32][64], swizzled
    __shared__ __align__(16) unsigned char sGb[TP * 1024];    // g bf16 [32][512], swizzled
    __shared__ float sGpart[NWAVE][TP];
    __shared__ float sGate[TP];

    const int tid  = threadIdx.x;
    const int lane = tid & 63;
    const int wave = tid >> 6;
    const int lr   = lane & 15;   // operand row / C col (position)
    const int lg   = lane >> 4;   // k-group / C row-quad
    const int pg0  = blockIdx.x * TP;
    const int b    = pg0 / TT;
    const int t0   = pg0 % TT;
    const int HR   = *p_hr;
    int NN = *p_mn - 1;
    if (NN > 3) NN = 3;
    if (NN < 0) NN = 0;

    const unsigned short* ws_whid = ws_bf;             // [512][64]
    const unsigned short* ws_wg1  = ws_bf + DD * EE;   // [256][512]

    // ---- P1: hash indices. 128 threads: tid = p*4 + h. Bit-exact fp32 replication.
    if (tid < TP * HH) {
        const int p = tid >> 2, h = tid & 3;
        const int t = t0 + p;
        const int* trow = tok + b * TT;
        const float sd = (float)(seeds[h] + 1);
        float w = (float)trow[t] * sd;
        for (int j = 0; j < NN; ++j) {
            const int n = j + 2;
            int idx = -1;
            if (t <= TT - n) {
                w = w + (float)trow[t + n - 1] * sd;
                idx = ((int)w) % HR;
            }
            sIdx[p][j][h] = idx;
        }
    }
    __syncthreads();

    // ---- P2: gather + head-mean + n-sum -> sMem bf16 [p][64] (swizzled)
    {
        const int p = tid >> 3, q = tid & 7;   // q covers e = q*8 .. q*8+7
        float acc[8];
        #pragma unroll
        for (int k = 0; k < 8; ++k) acc[k] = 0.f;
        for (int j = 0; j < NN; ++j) {
            #pragma unroll
            for (int h = 0; h < HH; ++h) {
                const int idx = sIdx[p][j][h];
                if (idx >= 0) {
                    const float* er = emb + ((size_t)h * 262144u + (size_t)idx) * EE + q * 8;
                    const float4 f0 = *(const float4*)(er);
                    const float4 f1 = *(const float4*)(er + 4);
                    acc[0] += f0.x; acc[1] += f0.y; acc[2] += f0.z; acc[3] += f0.w;
                    acc[4] += f1.x; acc[5] += f1.y; acc[6] += f1.z; acc[7] += f1.w;
                }
            }
        }
        s16x8 pk;
        #pragma unroll
        for (int k = 0; k < 8; ++k) pk[k] = (short)f2bf(acc[k] * 0.25f);
        const int c = q * 16;   // byte col
        *(s16x8*)(sMemb + p * 128 + (c ^ ((p & 7) << 4))) = pk;
    }
    __syncthreads();

    // ---- P3: projT[d][p]; g = hidden + proj + b_hid -> sGb (bf16, swizzled)
    {
        s16x8 bfrag[2][2];
        #pragma unroll
        for (int Nt = 0; Nt < 2; ++Nt)
            #pragma unroll
            for (int ks = 0; ks < 2; ++ks) {
                const int p = Nt * 16 + lr;
                const int c = ks * 64 + lg * 16;
                bfrag[Nt][ks] = *(const s16x8*)(sMemb + p * 128 + (c ^ ((p & 7) << 4)));
            }
        #pragma unroll 2
        for (int m = 0; m < 8; ++m) {
            const int Mt = wave * 8 + m;
            const int drow = Mt * 16 + lr;
            s16x8 afrag[2];
            #pragma unroll
            for (int ks = 0; ks < 2; ++ks)
                afrag[ks] = *(const s16x8*)(ws_whid + drow * EE + ks * 32 + lg * 8);
            #pragma unroll
            for (int Nt = 0; Nt < 2; ++Nt) {
                f32x4 c = {0.f, 0.f, 0.f, 0.f};
                c = __builtin_amdgcn_mfma_f32_16x16x32_bf16(afrag[0], bfrag[Nt][0], c, 0, 0, 0);
                c = __builtin_amdgcn_mfma_f32_16x16x32_bf16(afrag[1], bfrag[Nt][1], c, 0, 0, 0);
                // lane holds C[d = Mt*16+lg*4+r][p = Nt*16+lr]
                const int p_c = Nt * 16 + lr;
                const int d0  = Mt * 16 + lg * 4;
                const float4 hv = *(const float4*)&hidden[(size_t)(pg0 + p_c) * DD + d0];
                const float4 bh = *(const float4*)&b_hid[d0];
                s16x4 gp;
                gp[0] = (short)f2bf(hv.x + c[0] + bh.x);
                gp[1] = (short)f2bf(hv.y + c[1] + bh.y);
                gp[2] = (short)f2bf(hv.z + c[2] + bh.z);
                gp[3] = (short)f2bf(hv.w + c[3] + bh.w);
                const int cb = d0 * 2;
                *(s16x4*)(sGb + p_c * 1024 + (cb ^ ((p_c & 31) << 4))) = gp;
            }
        }
    }
    __syncthreads();

    // ---- P4: g1T[h][p] GEMM over K=512, consume into gate partials
    {
        float pgate[2] = {0.f, 0.f};
        #pragma unroll
        for (int Nt = 0; Nt < 2; ++Nt) {
            f32x4 c[4];
            #pragma unroll
            for (int m = 0; m < 4; ++m) c[m] = (f32x4){0.f, 0.f, 0.f, 0.f};
            const int p = Nt * 16 + lr;
            #pragma unroll 4
            for (int ks = 0; ks < 16; ++ks) {
                const int ccol = ks * 64 + lg * 16;
                const s16x8 gb = *(const s16x8*)(sGb + p * 1024 + (ccol ^ ((p & 31) << 4)));
                #pragma unroll
                for (int m = 0; m < 4; ++m) {
                    const int h0row = (wave * 4 + m) * 16 + lr;
                    const s16x8 a = *(const s16x8*)(ws_wg1 + (size_t)h0row * DD + ks * 32 + lg * 8);
                    c[m] = __builtin_amdgcn_mfma_f32_16x16x32_bf16(a, gb, c[m], 0, 0, 0);
                }
            }
            #pragma unroll
            for (int m = 0; m < 4; ++m) {
                // lane holds C[h = (wave*4+m)*16+lg*4+r][p = Nt*16+lr]
                const int h0 = (wave * 4 + m) * 16 + lg * 4;
                const float4 bg = *(const float4*)&b_g1[h0];
                const float4 w2 = *(const float4*)&W_g2[h0];
                #pragma unroll
                for (int r = 0; r < 4; ++r) {
                    const float x = c[m][r] + ((const float*)&bg)[r];
                    const float gl = 0.5f * x * (1.0f + erff(x * 0.70710678118654752f));
                    pgate[Nt] += gl * ((const float*)&w2)[r];
                }
            }
        }
        #pragma unroll
        for (int Nt = 0; Nt < 2; ++Nt) {
            pgate[Nt] += __shfl_xor(pgate[Nt], 16);
            pgate[Nt] += __shfl_xor(pgate[Nt], 32);
        }
        if (lane < 16) {
            #pragma unroll
            for (int Nt = 0; Nt < 2; ++Nt)
                sGpart[wave][Nt * 16 + lane] = pgate[Nt];
        }
    }
    __syncthreads();
    if (tid < TP) {
        const float s = sGpart[0][tid] + sGpart[1][tid] + sGpart[2][tid] + sGpart[3][tid] + b_g2[0];
        sGate[tid] = 1.0f / (1.0f + expf(-s));
    }
    __syncthreads();

    // ---- P6: out = hidden + gate*(g - hidden), lane-contiguous float4 NT stores
    {
        #pragma unroll
        for (int c4 = 0; c4 < 16; ++c4) {
            const int fidx = c4 * 256 + tid;          // float4 index in [0, 4096)
            const int p    = fidx >> 7;               // 128 float4 per position
            const int d    = (fidx & 127) * 4;
            const float gt = sGate[p];
            const size_t row = (size_t)(pg0 + p) * DD;
            const s16x4 gv = *(const s16x4*)(sGb + p * 1024 + ((d * 2) ^ ((p & 31) << 4)));
            const float4 h = *(const float4*)&hidden[row + d];
            f32x4 o;
            o[0] = h.x + gt * (bf2f((unsigned short)gv[0]) - h.x);
            o[1] = h.y + gt * (bf2f((unsigned short)gv[1]) - h.y);
            o[2] = h.z + gt * (bf2f((unsigned short)gv[2]) - h.z);
            o[3] = h.w + gt * (bf2f((unsigned short)gv[3]) - h.w);
            __builtin_nontemporal_store(o, (f32x4*)&out[row + d]);
        }
    }
}

extern "C" void kernel_launch(void* const* d_in, const int* in_sizes, int n_in,
                              void* d_out, int out_size, void* d_ws, size_t ws_size,
                              hipStream_t stream) {
    const int*   tok    = (const int*)  d_in[0];
    const float* hidden = (const float*)d_in[1];
    const float* emb    = (const float*)d_in[2];
    const float* W_hid  = (const float*)d_in[3];
    const float* b_hid  = (const float*)d_in[4];
    const float* W_g1   = (const float*)d_in[5];
    const float* b_g1   = (const float*)d_in[6];
    const float* W_g2   = (const float*)d_in[7];
    const float* b_g2   = (const float*)d_in[8];
    const int*   seeds  = (const int*)  d_in[9];
    const int*   p_hr   = (const int*)  d_in[10];
    const int*   p_mn   = (const int*)  d_in[11];
    float* out = (float*)d_out;
    unsigned short* ws_bf = (unsigned short*)d_ws;

    convert_weights<<<dim3((G1 * DD + 255) / 256), dim3(256), 0, stream>>>(W_hid, W_g1, ws_bf);

    const int npos = in_sizes[1] / DD;   // B*T
    engram_mfma<<<dim3(npos / TP), dim3(256), 0, stream>>>(
        tok, hidden, emb, b_hid, b_g1, W_g2, b_g2, seeds, p_hr, p_mn, ws_bf, out);
}

// Round 4
// 102.528 us; speedup vs baseline: 3.0617x; 1.0271x over previous
//
#include <hip/hip_runtime.h>
#include <math.h>

// Problem constants (match reference setup_inputs)
#define TT 4096
#define DD 512
#define EE 64
#define HH 4
#define G1 256      // D/2
#define TP 16       // positions per block
#define NWAVE 4

typedef short  s16x8 __attribute__((ext_vector_type(8)));
typedef short  s16x4 __attribute__((ext_vector_type(4)));
typedef float  f32x4 __attribute__((ext_vector_type(4)));

__device__ __forceinline__ unsigned short f2bf(float f) {
    union { float f; unsigned u; } v; v.f = f;
    unsigned r = v.u + 0x7FFFu + ((v.u >> 16) & 1u);   // RNE
    return (unsigned short)(r >> 16);
}
__device__ __forceinline__ float bf2f(unsigned short b) {
    union { unsigned u; float f; } v; v.u = ((unsigned)b) << 16;
    return v.f;
}

// ---- pre-pass: convert W_hid [512][64] and W_g1 [256][512] to bf16 in ws
__global__ __launch_bounds__(256) void convert_weights(
    const float* __restrict__ W_hid, const float* __restrict__ W_g1,
    unsigned short* __restrict__ ws) {
    int i = blockIdx.x * 256 + threadIdx.x;
    if (i < DD * EE)  ws[i] = f2bf(W_hid[i]);
    if (i < G1 * DD)  ws[DD * EE + i] = f2bf(W_g1[i]);
}

__global__ __launch_bounds__(256, 4) void engram_mfma(
    const int*   __restrict__ tok,     // [B,T]
    const float* __restrict__ hidden,  // [B,T,D]
    const float* __restrict__ emb,     // [H,HR,E]
    const float* __restrict__ b_hid,   // [D]
    const float* __restrict__ b_g1,    // [G1]
    const float* __restrict__ W_g2,    // [1,G1]
    const float* __restrict__ b_g2,    // [1]
    const int*   __restrict__ seeds,   // [H]
    const int*   __restrict__ p_hr,
    const int*   __restrict__ p_mn,
    const unsigned short* __restrict__ ws_bf,  // W_hid bf16 | W_g1 bf16
    float*       __restrict__ out)     // [B,T,D]
{
    __shared__ int   sIdx[TP][3][HH];
    __shared__ __align__(16) unsigned char sMemb[TP * 128];   // seq_mem bf16 [16][64], swizzled
    __shared__ __align__(16) unsigned char sGb[TP * 1024];    // g    bf16 [16][512], swizzled
    __shared__ __align__(16) unsigned char sPb[TP * 1024];    // proj bf16 [16][512], swizzled
    __shared__ float sGpart[NWAVE][TP];
    __shared__ float sGate[TP];

    const int tid  = threadIdx.x;
    const int lane = tid & 63;
    const int wave = tid >> 6;
    const int lr   = lane & 15;   // operand row / C col (position)
    const int lg   = lane >> 4;   // k-group / C row-quad
    const int pg0  = blockIdx.x * TP;
    const int b    = pg0 / TT;
    const int t0   = pg0 % TT;
    const int HR   = *p_hr;
    int NN = *p_mn - 1;
    if (NN > 3) NN = 3;
    if (NN < 0) NN = 0;

    const unsigned short* ws_whid = ws_bf;             // [512][64]
    const unsigned short* ws_wg1  = ws_bf + DD * EE;   // [256][512]

    // ---- P1: hash indices. 64 threads: tid = p*4 + h. Bit-exact fp32 replication.
    if (tid < TP * HH) {
        const int p = tid >> 2, h = tid & 3;
        const int t = t0 + p;
        const int* trow = tok + b * TT;
        const float sd = (float)(seeds[h] + 1);
        float w = (float)trow[t] * sd;
        for (int j = 0; j < NN; ++j) {
            const int n = j + 2;
            int idx = -1;
            if (t <= TT - n) {
                w = w + (float)trow[t + n - 1] * sd;
                idx = ((int)w) % HR;
            }
            sIdx[p][j][h] = idx;
        }
    }
    __syncthreads();

    // ---- P2: gather + head-mean + n-sum -> sMem bf16 [p][64] (swizzled)
    {
        const int p = tid >> 4, q = tid & 15;   // q covers e = q*4 .. q*4+3
        float acc[4] = {0.f, 0.f, 0.f, 0.f};
        for (int j = 0; j < NN; ++j) {
            #pragma unroll
            for (int h = 0; h < HH; ++h) {
                const int idx = sIdx[p][j][h];
                if (idx >= 0) {
                    const float4 f = *(const float4*)(emb + ((size_t)h * 262144u + (size_t)idx) * EE + q * 4);
                    acc[0] += f.x; acc[1] += f.y; acc[2] += f.z; acc[3] += f.w;
                }
            }
        }
        s16x4 pk;
        #pragma unroll
        for (int k = 0; k < 4; ++k) pk[k] = (short)f2bf(acc[k] * 0.25f);
        const int c = q * 8;   // byte col
        *(s16x4*)(sMemb + p * 128 + (c ^ ((p & 7) << 4))) = pk;
    }
    __syncthreads();

    // ---- P3: projT[d][p]; store g = h+proj+b (bf16) AND proj+b (bf16) to LDS
    {
        s16x8 bfrag[2];
        #pragma unroll
        for (int ks = 0; ks < 2; ++ks) {
            const int p = lr;
            const int c = ks * 64 + lg * 16;
            bfrag[ks] = *(const s16x8*)(sMemb + p * 128 + (c ^ ((p & 7) << 4)));
        }
        #pragma unroll 2
        for (int m = 0; m < 8; ++m) {
            const int Mt = wave * 8 + m;
            const int drow = Mt * 16 + lr;
            s16x8 afrag[2];
            #pragma unroll
            for (int ks = 0; ks < 2; ++ks)
                afrag[ks] = *(const s16x8*)(ws_whid + drow * EE + ks * 32 + lg * 8);
            f32x4 c = {0.f, 0.f, 0.f, 0.f};
            c = __builtin_amdgcn_mfma_f32_16x16x32_bf16(afrag[0], bfrag[0], c, 0, 0, 0);
            c = __builtin_amdgcn_mfma_f32_16x16x32_bf16(afrag[1], bfrag[1], c, 0, 0, 0);
            // lane holds C[d = Mt*16+lg*4+r][p = lr]
            const int p_c = lr;
            const int d0  = Mt * 16 + lg * 4;
            const float4 hv = *(const float4*)&hidden[(size_t)(pg0 + p_c) * DD + d0];
            const float4 bh = *(const float4*)&b_hid[d0];
            const float pr0 = c[0] + bh.x, pr1 = c[1] + bh.y;
            const float pr2 = c[2] + bh.z, pr3 = c[3] + bh.w;
            s16x4 gp, pp;
            gp[0] = (short)f2bf(hv.x + pr0);  pp[0] = (short)f2bf(pr0);
            gp[1] = (short)f2bf(hv.y + pr1);  pp[1] = (short)f2bf(pr1);
            gp[2] = (short)f2bf(hv.z + pr2);  pp[2] = (short)f2bf(pr2);
            gp[3] = (short)f2bf(hv.w + pr3);  pp[3] = (short)f2bf(pr3);
            const int cb = (d0 * 2) ^ ((p_c & 7) << 4);
            *(s16x4*)(sGb + p_c * 1024 + cb) = gp;
            *(s16x4*)(sPb + p_c * 1024 + cb) = pp;
        }
    }
    __syncthreads();

    // ---- P4: g1T[h][p] GEMM over K=512, consume into gate partials
    {
        float pgate = 0.f;
        f32x4 c[4];
        #pragma unroll
        for (int m = 0; m < 4; ++m) c[m] = (f32x4){0.f, 0.f, 0.f, 0.f};
        const int p = lr;
        #pragma unroll 4
        for (int ks = 0; ks < 16; ++ks) {
            const int ccol = ks * 64 + lg * 16;
            const s16x8 gb = *(const s16x8*)(sGb + p * 1024 + (ccol ^ ((p & 7) << 4)));
            #pragma unroll
            for (int m = 0; m < 4; ++m) {
                const int h0row = (wave * 4 + m) * 16 + lr;
                const s16x8 a = *(const s16x8*)(ws_wg1 + (size_t)h0row * DD + ks * 32 + lg * 8);
                c[m] = __builtin_amdgcn_mfma_f32_16x16x32_bf16(a, gb, c[m], 0, 0, 0);
            }
        }
        #pragma unroll
        for (int m = 0; m < 4; ++m) {
            // lane holds C[h = (wave*4+m)*16+lg*4+r][p = lr]
            const int h0 = (wave * 4 + m) * 16 + lg * 4;
            const float4 bg = *(const float4*)&b_g1[h0];
            const float4 w2 = *(const float4*)&W_g2[h0];
            #pragma unroll
            for (int r = 0; r < 4; ++r) {
                const float x = c[m][r] + ((const float*)&bg)[r];
                const float gl = 0.5f * x * (1.0f + erff(x * 0.70710678118654752f));
                pgate += gl * ((const float*)&w2)[r];
            }
        }
        pgate += __shfl_xor(pgate, 16);
        pgate += __shfl_xor(pgate, 32);
        if (lane < 16) sGpart[wave][lane] = pgate;
    }
    __syncthreads();
    if (tid < TP) {
        const float s = sGpart[0][tid] + sGpart[1][tid] + sGpart[2][tid] + sGpart[3][tid] + b_g2[0];
        sGate[tid] = 1.0f / (1.0f + expf(-s));
    }
    __syncthreads();

    // ---- P6: out = g - (1-gate)*proj  (no global reads), NT float4 stores
    {
        #pragma unroll
        for (int c4 = 0; c4 < 8; ++c4) {
            const int fidx = c4 * 256 + tid;          // float4 index in [0, 2048)
            const int p    = fidx >> 7;               // 128 float4 per position
            const int d    = (fidx & 127) * 4;
            const float cg = 1.0f - sGate[p];
            const size_t row = (size_t)(pg0 + p) * DD;
            const int cb = (d * 2) ^ ((p & 7) << 4);
            const s16x4 gv = *(const s16x4*)(sGb + p * 1024 + cb);
            const s16x4 pv = *(const s16x4*)(sPb + p * 1024 + cb);
            f32x4 o;
            o[0] = bf2f((unsigned short)gv[0]) - cg * bf2f((unsigned short)pv[0]);
            o[1] = bf2f((unsigned short)gv[1]) - cg * bf2f((unsigned short)pv[1]);
            o[2] = bf2f((unsigned short)gv[2]) - cg * bf2f((unsigned short)pv[2]);
            o[3] = bf2f((unsigned short)gv[3]) - cg * bf2f((unsigned short)pv[3]);
            __builtin_nontemporal_store(o, (f32x4*)&out[row + d]);
        }
    }
}

extern "C" void kernel_launch(void* const* d_in, const int* in_sizes, int n_in,
                              void* d_out, int out_size, void* d_ws, size_t ws_size,
                              hipStream_t stream) {
    const int*   tok    = (const int*)  d_in[0];
    const float* hidden = (const float*)d_in[1];
    const float* emb    = (const float*)d_in[2];
    const float* W_hid  = (const float*)d_in[3];
    const float* b_hid  = (const float*)d_in[4];
    const float* W_g1   = (const float*)d_in[5];
    const float* b_g1   = (const float*)d_in[6];
    const float* W_g2   = (const float*)d_in[7];
    const float* b_g2   = (const float*)d_in[8];
    const int*   seeds  = (const int*)  d_in[9];
    const int*   p_hr   = (const int*)  d_in[10];
    const int*   p_mn   = (const int*)  d_in[11];
    float* out = (float*)d_out;
    unsigned short* ws_bf = (unsigned short*)d_ws;

    convert_weights<<<dim3((G1 * DD + 255) / 256), dim3(256), 0, stream>>>(W_hid, W_g1, ws_bf);

    const int npos = in_sizes[1] / DD;   // B*T
    engram_mfma<<<dim3(npos / TP), dim3(256), 0, stream>>>(
        tok, hidden, emb, b_hid, b_g1, W_g2, b_g2, seeds, p_hr, p_mn, ws_bf, out);
}